// Round 1
// baseline (2820.715 us; speedup 1.0000x reference)
//
#include <hip/hip_runtime.h>
#include <hip/hip_bf16.h>
#include <cstdint>

#define N_TOK   4096
#define D_MODEL 1024
#define N_HEAD  16
#define DH      64
#define INNER   2816

__device__ __forceinline__ float silu_f(float x) {
    return x / (1.f + __expf(-x));
}

// ---------------------------------------------------------------------------
// Generic tiled fp32 GEMM: C[M,N] = A[M,K] @ B[K,N], row-major.
// 64x64 tile, 256 threads, 4x4 micro-tile, BK=16. A-tile padded +1 (bank).
// M,N multiples of 64; K multiple of 16 (true for all 5 calls here).
// ---------------------------------------------------------------------------
__global__ __launch_bounds__(256) void gemm64(
    const float* __restrict__ A, const float* __restrict__ B,
    float* __restrict__ C, int M, int N, int K, int ldb, int ldc) {
    __shared__ float As[64][17];
    __shared__ float Bs[16][64];
    const int tid = threadIdx.x;
    const int tr = tid >> 4, tc = tid & 15;
    const int rowBase = blockIdx.y * 64;
    const int colBase = blockIdx.x * 64;
    const int ar = tid >> 2, ac = (tid & 3) * 4;   // A staging coords
    const int br = tid >> 4, bc = (tid & 15) * 4;  // B staging coords
    float acc[4][4] = {};
    for (int k0 = 0; k0 < K; k0 += 16) {
        float4 a4 = *reinterpret_cast<const float4*>(
            &A[(size_t)(rowBase + ar) * K + k0 + ac]);
        float4 b4 = *reinterpret_cast<const float4*>(
            &B[(size_t)(k0 + br) * ldb + colBase + bc]);
        As[ar][ac]     = a4.x; As[ar][ac + 1] = a4.y;
        As[ar][ac + 2] = a4.z; As[ar][ac + 3] = a4.w;
        *reinterpret_cast<float4*>(&Bs[br][bc]) = b4;
        __syncthreads();
#pragma unroll
        for (int kk = 0; kk < 16; ++kk) {
            float a[4], b[4];
#pragma unroll
            for (int i = 0; i < 4; ++i) a[i] = As[tr * 4 + i][kk];
            float4 bb = *reinterpret_cast<const float4*>(&Bs[kk][tc * 4]);
            b[0] = bb.x; b[1] = bb.y; b[2] = bb.z; b[3] = bb.w;
#pragma unroll
            for (int i = 0; i < 4; ++i)
#pragma unroll
                for (int j = 0; j < 4; ++j) acc[i][j] += a[i] * b[j];
        }
        __syncthreads();
    }
#pragma unroll
    for (int i = 0; i < 4; ++i) {
        float4 o;
        o.x = acc[i][0]; o.y = acc[i][1]; o.z = acc[i][2]; o.w = acc[i][3];
        *reinterpret_cast<float4*>(
            &C[(size_t)(rowBase + tr * 4 + i) * ldc + colBase + tc * 4]) = o;
    }
}

// ---------------------------------------------------------------------------
// RoPE + RMS-norm + transpose for Q,K; transpose for V.
// One wave per (token n, head h). qkv layout [N][3][H][DH].
// Outputs [H][N][DH].
// ---------------------------------------------------------------------------
__global__ __launch_bounds__(256) void rope_norm(
    const float* __restrict__ qkv, const float* __restrict__ cosb,
    const float* __restrict__ sinb, float* __restrict__ Qn,
    float* __restrict__ Kn, float* __restrict__ Vn) {
    const int w = blockIdx.x * 4 + (threadIdx.x >> 6);  // wave id 0..65535
    const int lane = threadIdx.x & 63;
    const int n = w >> 4, h = w & 15;
    const float* base = qkv + (size_t)n * (3 * D_MODEL) + h * DH;
    float q = base[lane];
    float k = base[D_MODEL + lane];
    float v = base[2 * D_MODEL + lane];
    const float c = cosb[n * DH + lane];
    const float s = sinb[n * DH + lane];
    const float qp = __shfl(q, lane ^ 32, 64);
    const float kp = __shfl(k, lane ^ 32, 64);
    const float sgn = (lane < 32) ? -1.f : 1.f;
    q = q * c + sgn * qp * s;
    k = k * c + sgn * kp * s;
    float sq = q * q, sk = k * k;
#pragma unroll
    for (int off = 32; off > 0; off >>= 1) {
        sq += __shfl_xor(sq, off, 64);
        sk += __shfl_xor(sk, off, 64);
    }
    q *= rsqrtf(sq * (1.f / DH) + 1e-5f);
    k *= rsqrtf(sk * (1.f / DH) + 1e-5f);
    const size_t o = ((size_t)h * N_TOK + n) * DH + lane;
    Qn[o] = q; Kn[o] = k; Vn[o] = v;
}

// ---------------------------------------------------------------------------
// Linear attention: per (head, 64-query tile), stream 64-key tiles.
// W = (elu(S/8)+1)^2 ; acc += W@V ; denom += rowsum(W); out = acc/denom - V.
// Output written directly in m_concat layout [N][D_MODEL].
// ---------------------------------------------------------------------------
__global__ __launch_bounds__(256) void attn_lin(
    const float* __restrict__ Qn, const float* __restrict__ Kn,
    const float* __restrict__ Vn, float* __restrict__ Mout) {
    const int h = blockIdx.y;
    const int q0 = blockIdx.x * 64;
    __shared__ float Qs[64][65];
    __shared__ float Ks[64][65];
    __shared__ float Vs[64][64];
    __shared__ float Ws[64][65];
    const int tid = threadIdx.x;
    const int tr16 = tid >> 4, tc16 = tid & 15;
    const float* Qh = Qn + (size_t)h * N_TOK * DH;
    const float* Kh = Kn + (size_t)h * N_TOK * DH;
    const float* Vh = Vn + (size_t)h * N_TOK * DH;
    // stage Q tile (64x64)
#pragma unroll
    for (int p = 0; p < 4; ++p) {
        const int f = p * 256 + tid;
        const int r = f >> 4, c = (f & 15) * 4;
        float4 v4 = *reinterpret_cast<const float4*>(&Qh[(size_t)(q0 + r) * DH + c]);
        Qs[r][c] = v4.x; Qs[r][c + 1] = v4.y; Qs[r][c + 2] = v4.z; Qs[r][c + 3] = v4.w;
    }
    float acc[4][4] = {};
    float dpart[4] = {};
    for (int kt = 0; kt < N_TOK / 64; ++kt) {
        __syncthreads();  // prev phase-2 done (and Q staged, 1st iter)
        const int k0 = kt * 64;
#pragma unroll
        for (int p = 0; p < 4; ++p) {
            const int f = p * 256 + tid;
            const int r = f >> 4, c = (f & 15) * 4;
            float4 kv = *reinterpret_cast<const float4*>(&Kh[(size_t)(k0 + r) * DH + c]);
            Ks[r][c] = kv.x; Ks[r][c + 1] = kv.y; Ks[r][c + 2] = kv.z; Ks[r][c + 3] = kv.w;
            float4 vv = *reinterpret_cast<const float4*>(&Vh[(size_t)(k0 + r) * DH + c]);
            *reinterpret_cast<float4*>(&Vs[r][c]) = vv;
        }
        __syncthreads();
        // phase 1: S tile (4x4 per thread)
        float s[4][4] = {};
#pragma unroll 16
        for (int dd = 0; dd < 64; ++dd) {
            float a[4], b[4];
#pragma unroll
            for (int i = 0; i < 4; ++i) a[i] = Qs[tr16 * 4 + i][dd];
#pragma unroll
            for (int j = 0; j < 4; ++j) b[j] = Ks[tc16 * 4 + j][dd];
#pragma unroll
            for (int i = 0; i < 4; ++i)
#pragma unroll
                for (int j = 0; j < 4; ++j) s[i][j] += a[i] * b[j];
        }
#pragma unroll
        for (int i = 0; i < 4; ++i) {
            float part = 0.f;
#pragma unroll
            for (int j = 0; j < 4; ++j) {
                float wv = s[i][j] * 0.125f;           // * dh^-0.5
                wv = (wv > 0.f) ? (wv + 1.f) : __expf(wv);  // elu+1
                wv = wv * wv;
                Ws[tr16 * 4 + i][tc16 * 4 + j] = wv;
                part += wv;
            }
            dpart[i] += part;
        }
        __syncthreads();
        // phase 2: acc += W @ V
#pragma unroll 8
        for (int m = 0; m < 64; ++m) {
            float w0 = Ws[tr16 * 4 + 0][m], w1 = Ws[tr16 * 4 + 1][m];
            float w2 = Ws[tr16 * 4 + 2][m], w3 = Ws[tr16 * 4 + 3][m];
            float4 vv = *reinterpret_cast<const float4*>(&Vs[m][tc16 * 4]);
            acc[0][0] += w0 * vv.x; acc[0][1] += w0 * vv.y; acc[0][2] += w0 * vv.z; acc[0][3] += w0 * vv.w;
            acc[1][0] += w1 * vv.x; acc[1][1] += w1 * vv.y; acc[1][2] += w1 * vv.z; acc[1][3] += w1 * vv.w;
            acc[2][0] += w2 * vv.x; acc[2][1] += w2 * vv.y; acc[2][2] += w2 * vv.z; acc[2][3] += w2 * vv.w;
            acc[3][0] += w3 * vv.x; acc[3][1] += w3 * vv.y; acc[3][2] += w3 * vv.z; acc[3][3] += w3 * vv.w;
        }
    }
    // denominator: reduce across the 16 threads (same tr16) sharing each row
#pragma unroll
    for (int i = 0; i < 4; ++i) {
#pragma unroll
        for (int off = 1; off < 16; off <<= 1) dpart[i] += __shfl_xor(dpart[i], off, 16);
    }
#pragma unroll
    for (int i = 0; i < 4; ++i) {
        const int r = tr16 * 4 + i;
        const float dn = 1.f / (dpart[i] + 1e-6f);
        float4 vv = *reinterpret_cast<const float4*>(&Vh[(size_t)(q0 + r) * DH + tc16 * 4]);
        float4 o;
        o.x = acc[i][0] * dn - vv.x; o.y = acc[i][1] * dn - vv.y;
        o.z = acc[i][2] * dn - vv.z; o.w = acc[i][3] * dn - vv.w;
        *reinterpret_cast<float4*>(
            &Mout[(size_t)(q0 + r) * D_MODEL + h * DH + tc16 * 4]) = o;
    }
}

// ---------------------------------------------------------------------------
// O[row] = rmsnorm(X[row] + R[row]), row length D_MODEL, 256 thr/row.
// ---------------------------------------------------------------------------
__global__ __launch_bounds__(256) void rms_resid(
    const float* __restrict__ X, const float* __restrict__ R,
    float* __restrict__ O) {
    const int row = blockIdx.x;
    const int tid = threadIdx.x;
    const float4 xv = reinterpret_cast<const float4*>(X + (size_t)row * D_MODEL)[tid];
    const float4 rv = reinterpret_cast<const float4*>(R + (size_t)row * D_MODEL)[tid];
    const float t0 = xv.x + rv.x, t1 = xv.y + rv.y, t2 = xv.z + rv.z, t3 = xv.w + rv.w;
    float ss = t0 * t0 + t1 * t1 + t2 * t2 + t3 * t3;
#pragma unroll
    for (int off = 32; off > 0; off >>= 1) ss += __shfl_xor(ss, off, 64);
    __shared__ float red[4];
    if ((tid & 63) == 0) red[tid >> 6] = ss;
    __syncthreads();
    const float tot = red[0] + red[1] + red[2] + red[3];
    const float rs = rsqrtf(tot * (1.f / D_MODEL) + 1e-5f);
    float4 o;
    o.x = t0 * rs; o.y = t1 * rs; o.z = t2 * rs; o.w = t3 * rs;
    reinterpret_cast<float4*>(O + (size_t)row * D_MODEL)[tid] = o;
}

// Hf = silu(G) * U (elementwise, in-place into G allowed)
__global__ __launch_bounds__(256) void silu_mul(
    const float* __restrict__ G, const float* __restrict__ U,
    float* __restrict__ Hf) {
    const size_t idx = (size_t)blockIdx.x * 256 + threadIdx.x;
    float4 g = reinterpret_cast<const float4*>(G)[idx];
    float4 u = reinterpret_cast<const float4*>(U)[idx];
    float4 o;
    o.x = silu_f(g.x) * u.x; o.y = silu_f(g.y) * u.y;
    o.z = silu_f(g.z) * u.z; o.w = silu_f(g.w) * u.w;
    reinterpret_cast<float4*>(Hf)[idx] = o;
}

// depthwise conv k=3 pad=1 over tokens + bias + silu
__global__ __launch_bounds__(256) void dwconv(
    const float* __restrict__ Hf, const float* __restrict__ W,
    const float* __restrict__ Bv, float* __restrict__ Hc) {
    const size_t idx = (size_t)blockIdx.x * 256 + threadIdx.x;
    const int c4 = (int)(idx % (INNER / 4)) * 4;
    const int n = (int)(idx / (INNER / 4));
    float4 acc = *reinterpret_cast<const float4*>(&Bv[c4]);
#pragma unroll
    for (int k = 0; k < 3; ++k) {
        const int nn = n + k - 1;
        if (nn >= 0 && nn < N_TOK) {
            float4 x = *reinterpret_cast<const float4*>(&Hf[(size_t)nn * INNER + c4]);
            float4 w = *reinterpret_cast<const float4*>(&W[(size_t)k * INNER + c4]);
            acc.x += x.x * w.x; acc.y += x.y * w.y;
            acc.z += x.z * w.z; acc.w += x.w * w.w;
        }
    }
    acc.x = silu_f(acc.x); acc.y = silu_f(acc.y);
    acc.z = silu_f(acc.z); acc.w = silu_f(acc.w);
    *reinterpret_cast<float4*>(&Hc[(size_t)n * INNER + c4]) = acc;
}

extern "C" void kernel_launch(void* const* d_in, const int* in_sizes, int n_in,
                              void* d_out, int out_size, void* d_ws, size_t ws_size,
                              hipStream_t stream) {
    const float* Qin   = (const float*)d_in[0];
    const float* cosb  = (const float*)d_in[1];
    const float* sinb  = (const float*)d_in[2];
    const float* Wqkv  = (const float*)d_in[3];
    const float* Wo    = (const float*)d_in[4];
    const float* Wup   = (const float*)d_in[5];
    const float* convw = (const float*)d_in[6];
    const float* convb = (const float*)d_in[7];
    const float* Wdown = (const float*)d_in[8];
    float* out = (float*)d_out;
    float* ws  = (float*)d_ws;

    // workspace layout (floats); peak = 35,651,584 floats = 136 MiB
    float* qkv      = ws;                    // [4096][3072]
    float* Qn       = ws + 12582912;         // [16][4096][64]
    float* Kn       = Qn + 4194304;
    float* Vn       = Kn + 4194304;
    float* mcat     = Vn + 4194304;          // [4096][1024]  (ends 29,360,128)
    float* wo_out   = ws;                    // reuse qkv region
    float* Qi       = ws + 4194304;          // alive till end
    float* Gbuf     = ws + 12582912;         // [4096][2816] (reuse Qn/Kn)
    float* Ubuf     = ws + 24117248;         // [4096][2816] (reuse mcat tail)
    float* down_out = ws;                    // reuse wo_out

    const dim3 blk(256);
    // 1. QKV projection
    gemm64<<<dim3(3072 / 64, 4096 / 64), blk, 0, stream>>>(
        Qin, Wqkv, qkv, 4096, 3072, 1024, 3072, 3072);
    // 2. RoPE + RMS + transpose
    rope_norm<<<16384, blk, 0, stream>>>(qkv, cosb, sinb, Qn, Kn, Vn);
    // 3. attention -> m_concat
    attn_lin<<<dim3(64, 16), blk, 0, stream>>>(Qn, Kn, Vn, mcat);
    // 4. W_o projection
    gemm64<<<dim3(1024 / 64, 4096 / 64), blk, 0, stream>>>(
        mcat, Wo, wo_out, 4096, 1024, 1024, 1024, 1024);
    // 5. Q_interact = rmsnorm(Q_in + wo_out)
    rms_resid<<<4096, blk, 0, stream>>>(wo_out, Qin, Qi);
    // 6. G / U halves of W_up
    gemm64<<<dim3(2816 / 64, 4096 / 64), blk, 0, stream>>>(
        Qi, Wup, Gbuf, 4096, 2816, 1024, 5632, 2816);
    gemm64<<<dim3(2816 / 64, 4096 / 64), blk, 0, stream>>>(
        Qi, Wup + 2816, Ubuf, 4096, 2816, 1024, 5632, 2816);
    // 7. Hf = silu(G)*U (in-place into Gbuf)
    silu_mul<<<(4096 * (INNER / 4)) / 256, blk, 0, stream>>>(Gbuf, Ubuf, Gbuf);
    // 8. depthwise conv + bias + silu -> Ubuf
    dwconv<<<(4096 * (INNER / 4)) / 256, blk, 0, stream>>>(Gbuf, convw, convb, Ubuf);
    // 9. W_down projection
    gemm64<<<dim3(1024 / 64, 4096 / 64), blk, 0, stream>>>(
        Ubuf, Wdown, down_out, 4096, 1024, 2816, 1024, 1024);
    // 10. out = rmsnorm(Qi + down_out)
    rms_resid<<<4096, blk, 0, stream>>>(down_out, Qi, out);
}

// Round 2
// 2064.453 us; speedup vs baseline: 1.3663x; 1.3663x over previous
//
#include <hip/hip_runtime.h>
#include <hip/hip_bf16.h>
#include <cstdint>

#define N_TOK   4096
#define D_MODEL 1024
#define N_HEAD  16
#define DH      64
#define INNER   2816

typedef __attribute__((ext_vector_type(8))) short bf16x8;
typedef __attribute__((ext_vector_type(4))) float f32x4;
typedef __attribute__((ext_vector_type(8))) unsigned short us8v;

union BF16x8U { bf16x8 v; uint32_t u[4]; };

__device__ __forceinline__ unsigned short f2bf(float x) {
    union { __hip_bfloat16 h; unsigned short u; } c;
    c.h = __float2bfloat16(x);
    return c.u;
}

__device__ __forceinline__ float silu_f(float x) {
    return x / (1.f + __expf(-x));
}

// ---------------------------------------------------------------------------
// Generic tiled fp32 GEMM: C[M,N] = A[M,K] @ B[K,N], row-major. (unchanged)
// ---------------------------------------------------------------------------
__global__ __launch_bounds__(256) void gemm64(
    const float* __restrict__ A, const float* __restrict__ B,
    float* __restrict__ C, int M, int N, int K, int ldb, int ldc) {
    __shared__ float As[64][17];
    __shared__ float Bs[16][64];
    const int tid = threadIdx.x;
    const int tr = tid >> 4, tc = tid & 15;
    const int rowBase = blockIdx.y * 64;
    const int colBase = blockIdx.x * 64;
    const int ar = tid >> 2, ac = (tid & 3) * 4;
    const int br = tid >> 4, bc = (tid & 15) * 4;
    float acc[4][4] = {};
    for (int k0 = 0; k0 < K; k0 += 16) {
        float4 a4 = *reinterpret_cast<const float4*>(
            &A[(size_t)(rowBase + ar) * K + k0 + ac]);
        float4 b4 = *reinterpret_cast<const float4*>(
            &B[(size_t)(k0 + br) * ldb + colBase + bc]);
        As[ar][ac]     = a4.x; As[ar][ac + 1] = a4.y;
        As[ar][ac + 2] = a4.z; As[ar][ac + 3] = a4.w;
        *reinterpret_cast<float4*>(&Bs[br][bc]) = b4;
        __syncthreads();
#pragma unroll
        for (int kk = 0; kk < 16; ++kk) {
            float a[4], b[4];
#pragma unroll
            for (int i = 0; i < 4; ++i) a[i] = As[tr * 4 + i][kk];
            float4 bb = *reinterpret_cast<const float4*>(&Bs[kk][tc * 4]);
            b[0] = bb.x; b[1] = bb.y; b[2] = bb.z; b[3] = bb.w;
#pragma unroll
            for (int i = 0; i < 4; ++i)
#pragma unroll
                for (int j = 0; j < 4; ++j) acc[i][j] += a[i] * b[j];
        }
        __syncthreads();
    }
#pragma unroll
    for (int i = 0; i < 4; ++i) {
        float4 o;
        o.x = acc[i][0]; o.y = acc[i][1]; o.z = acc[i][2]; o.w = acc[i][3];
        *reinterpret_cast<float4*>(
            &C[(size_t)(rowBase + tr * 4 + i) * ldc + colBase + tc * 4]) = o;
    }
}

// ---------------------------------------------------------------------------
// RoPE + RMS-norm; emits Qb,Kb [h][n][d] bf16, Vt [h][d][n] bf16 (LDS
// transpose), Vn [h][n][d] fp32. Block = (64-token chunk, head).
// ---------------------------------------------------------------------------
__global__ __launch_bounds__(256) void rope_norm2(
    const float* __restrict__ qkv, const float* __restrict__ cosb,
    const float* __restrict__ sinb, unsigned short* __restrict__ Qb,
    unsigned short* __restrict__ Kb, unsigned short* __restrict__ Vt,
    float* __restrict__ Vn) {
    const int h = blockIdx.y;
    const int n0 = blockIdx.x * 64;
    const int wv = threadIdx.x >> 6;
    const int lane = threadIdx.x & 63;
    __shared__ unsigned short Vs[64][66];
#pragma unroll 1
    for (int it = 0; it < 16; ++it) {
        const int tn = it * 4 + wv;
        const int n = n0 + tn;
        const float* base = qkv + (size_t)n * (3 * D_MODEL) + h * DH;
        float qv = base[lane];
        float kv = base[D_MODEL + lane];
        float vv = base[2 * D_MODEL + lane];
        const float c = cosb[n * DH + lane];
        const float s = sinb[n * DH + lane];
        const float qp = __shfl(qv, lane ^ 32, 64);
        const float kp = __shfl(kv, lane ^ 32, 64);
        const float sgn = (lane < 32) ? -1.f : 1.f;
        qv = qv * c + sgn * qp * s;
        kv = kv * c + sgn * kp * s;
        float sq = qv * qv, sk = kv * kv;
#pragma unroll
        for (int off = 32; off > 0; off >>= 1) {
            sq += __shfl_xor(sq, off, 64);
            sk += __shfl_xor(sk, off, 64);
        }
        qv *= rsqrtf(sq * (1.f / DH) + 1e-5f);
        kv *= rsqrtf(sk * (1.f / DH) + 1e-5f);
        const size_t o = ((size_t)h * N_TOK + n) * DH + lane;
        Qb[o] = f2bf(qv);
        Kb[o] = f2bf(kv);
        Vn[o] = vv;
        Vs[tn][lane] = f2bf(vv);
    }
    __syncthreads();
    const int d = threadIdx.x >> 2;
    const int c0 = (threadIdx.x & 3) * 16;
    us8v o0, o1;
#pragma unroll
    for (int i = 0; i < 8; ++i) o0[i] = Vs[c0 + i][d];
#pragma unroll
    for (int i = 0; i < 8; ++i) o1[i] = Vs[c0 + 8 + i][d];
    unsigned short* dst = Vt + ((size_t)h * DH + d) * N_TOK + n0 + c0;
    *reinterpret_cast<us8v*>(dst) = o0;
    *reinterpret_cast<us8v*>(dst + 8) = o1;
}

// ---------------------------------------------------------------------------
// MFMA linear attention, zero LDS. Per block: 64 queries x 1 head; 4 waves,
// each owns 16 q. S^T = mfma(K_rows, Q_rows); W=(elu(S/8)+1)^2 in regs;
// denom accumulates per-lane (one q column per lane); W repacked to PV
// B-operand via 16 shfls; C^T = mfma(V^T_rows, W^T) accumulated over keys.
// Out: M[q][h*64+d] = C/denom - V.
// ---------------------------------------------------------------------------
__global__ __launch_bounds__(256) void attn_mfma(
    const unsigned short* __restrict__ Qb, const unsigned short* __restrict__ Kb,
    const unsigned short* __restrict__ Vt, const float* __restrict__ Vn,
    float* __restrict__ Mout) {
    const int h = blockIdx.y;
    const int q0 = blockIdx.x * 64;
    const int lane = threadIdx.x & 63;
    const int wv = threadIdx.x >> 6;
    const int l15 = lane & 15, lg = lane >> 4;
    const int qw = q0 + wv * 16;
    const unsigned short* Qh = Qb + (size_t)h * N_TOK * DH;
    const unsigned short* Kh = Kb + (size_t)h * N_TOK * DH;
    const unsigned short* Vth = Vt + (size_t)h * DH * N_TOK;

    const bf16x8 qf0 = *reinterpret_cast<const bf16x8*>(
        Qh + (size_t)(qw + l15) * DH + lg * 8);
    const bf16x8 qf1 = *reinterpret_cast<const bf16x8*>(
        Qh + (size_t)(qw + l15) * DH + 32 + lg * 8);

    f32x4 ct[4];
#pragma unroll
    for (int i = 0; i < 4; ++i) ct[i] = (f32x4){0.f, 0.f, 0.f, 0.f};
    float dpart = 0.f;

    for (int k0 = 0; k0 < N_TOK; k0 += 64) {
        // K fragments (A-style rows), 8 x 16B
        const unsigned short* kp = Kh + (size_t)(k0 + l15) * DH + lg * 8;
        bf16x8 kf[4][2];
#pragma unroll
        for (int ks = 0; ks < 4; ++ks) {
            kf[ks][0] = *reinterpret_cast<const bf16x8*>(kp + ks * 16 * DH);
            kf[ks][1] = *reinterpret_cast<const bf16x8*>(kp + ks * 16 * DH + 32);
        }
        // V^T fragments from Vt[h][d][n], 8 x 16B (issued early, used in PV)
        const unsigned short* vp = Vth + (size_t)l15 * N_TOK + k0 + lg * 8;
        bf16x8 vf[4][2];
#pragma unroll
        for (int ds = 0; ds < 4; ++ds) {
            vf[ds][0] = *reinterpret_cast<const bf16x8*>(vp + (size_t)ds * 16 * N_TOK);
            vf[ds][1] = *reinterpret_cast<const bf16x8*>(vp + (size_t)ds * 16 * N_TOK + 32);
        }
        // S^T subtiles: lane holds W^T[k=ks*16+lg*4+r][q=qw+l15]
        f32x4 st[4];
#pragma unroll
        for (int ks = 0; ks < 4; ++ks) {
            f32x4 z = (f32x4){0.f, 0.f, 0.f, 0.f};
            z = __builtin_amdgcn_mfma_f32_16x16x32_bf16(kf[ks][0], qf0, z, 0, 0, 0);
            st[ks] = __builtin_amdgcn_mfma_f32_16x16x32_bf16(kf[ks][1], qf1, st[ks] = z, 0, 0, 0);
        }
        // W = (elu(s/8)+1)^2 ; per-lane denom ; pack to bf16 pairs
        uint32_t wpk[4][2];
#pragma unroll
        for (int ks = 0; ks < 4; ++ks) {
            float w[4];
#pragma unroll
            for (int r = 0; r < 4; ++r) {
                const float x = st[ks][r] * 0.125f;
                float e = fmaxf(x, 0.f) + __expf(fminf(x, 0.f));
                e = e * e;
                w[r] = e;
                dpart += e;
            }
            wpk[ks][0] = (uint32_t)f2bf(w[0]) | ((uint32_t)f2bf(w[1]) << 16);
            wpk[ks][1] = (uint32_t)f2bf(w[2]) | ((uint32_t)f2bf(w[3]) << 16);
        }
        // Repack W^T C-frags -> PV B-operand. Target lane needs
        // k' = kh*32 + lg*8 + j from frag ksub=2kh+(lg>>1), src lanes
        // l15 + 32*(lg&1) (+16). Shfl both ksub candidates, select by lg&2.
        const int sA = l15 + ((lg & 1) << 5);
        const int sB = sA + 16;
        const bool hi = (lg & 2) != 0;
#pragma unroll
        for (int kh = 0; kh < 2; ++kh) {
            const uint32_t a0 = (uint32_t)__shfl((int)wpk[2 * kh][0], sA, 64);
            const uint32_t a1 = (uint32_t)__shfl((int)wpk[2 * kh][1], sA, 64);
            const uint32_t a2 = (uint32_t)__shfl((int)wpk[2 * kh][0], sB, 64);
            const uint32_t a3 = (uint32_t)__shfl((int)wpk[2 * kh][1], sB, 64);
            const uint32_t b0 = (uint32_t)__shfl((int)wpk[2 * kh + 1][0], sA, 64);
            const uint32_t b1 = (uint32_t)__shfl((int)wpk[2 * kh + 1][1], sA, 64);
            const uint32_t b2 = (uint32_t)__shfl((int)wpk[2 * kh + 1][0], sB, 64);
            const uint32_t b3 = (uint32_t)__shfl((int)wpk[2 * kh + 1][1], sB, 64);
            BF16x8U bb;
            bb.u[0] = hi ? b0 : a0;
            bb.u[1] = hi ? b1 : a1;
            bb.u[2] = hi ? b2 : a2;
            bb.u[3] = hi ? b3 : a3;
#pragma unroll
            for (int ds = 0; ds < 4; ++ds)
                ct[ds] = __builtin_amdgcn_mfma_f32_16x16x32_bf16(
                    vf[ds][kh], bb.v, ct[ds], 0, 0, 0);
        }
    }
    // denom: lanes {l, l^16, l^32, l^48} share q
    dpart += __shfl_xor(dpart, 16, 64);
    dpart += __shfl_xor(dpart, 32, 64);
    const float dn = 1.f / (dpart + 1e-6f);
    const float* Vh = Vn + (size_t)h * N_TOK * DH;
    const int q = qw + l15;
#pragma unroll
    for (int ds = 0; ds < 4; ++ds) {
        const int d = ds * 16 + lg * 4;
        const float4 vv = *reinterpret_cast<const float4*>(&Vh[(size_t)q * DH + d]);
        float4 o;
        o.x = ct[ds][0] * dn - vv.x;
        o.y = ct[ds][1] * dn - vv.y;
        o.z = ct[ds][2] * dn - vv.z;
        o.w = ct[ds][3] * dn - vv.w;
        *reinterpret_cast<float4*>(&Mout[(size_t)q * D_MODEL + h * DH + d]) = o;
    }
}

// ---------------------------------------------------------------------------
// O[row] = rmsnorm(X[row] + R[row]) (unchanged)
// ---------------------------------------------------------------------------
__global__ __launch_bounds__(256) void rms_resid(
    const float* __restrict__ X, const float* __restrict__ R,
    float* __restrict__ O) {
    const int row = blockIdx.x;
    const int tid = threadIdx.x;
    const float4 xv = reinterpret_cast<const float4*>(X + (size_t)row * D_MODEL)[tid];
    const float4 rv = reinterpret_cast<const float4*>(R + (size_t)row * D_MODEL)[tid];
    const float t0 = xv.x + rv.x, t1 = xv.y + rv.y, t2 = xv.z + rv.z, t3 = xv.w + rv.w;
    float ss = t0 * t0 + t1 * t1 + t2 * t2 + t3 * t3;
#pragma unroll
    for (int off = 32; off > 0; off >>= 1) ss += __shfl_xor(ss, off, 64);
    __shared__ float red[4];
    if ((tid & 63) == 0) red[tid >> 6] = ss;
    __syncthreads();
    const float tot = red[0] + red[1] + red[2] + red[3];
    const float rs = rsqrtf(tot * (1.f / D_MODEL) + 1e-5f);
    float4 o;
    o.x = t0 * rs; o.y = t1 * rs; o.z = t2 * rs; o.w = t3 * rs;
    reinterpret_cast<float4*>(O + (size_t)row * D_MODEL)[tid] = o;
}

__global__ __launch_bounds__(256) void silu_mul(
    const float* __restrict__ G, const float* __restrict__ U,
    float* __restrict__ Hf) {
    const size_t idx = (size_t)blockIdx.x * 256 + threadIdx.x;
    float4 g = reinterpret_cast<const float4*>(G)[idx];
    float4 u = reinterpret_cast<const float4*>(U)[idx];
    float4 o;
    o.x = silu_f(g.x) * u.x; o.y = silu_f(g.y) * u.y;
    o.z = silu_f(g.z) * u.z; o.w = silu_f(g.w) * u.w;
    reinterpret_cast<float4*>(Hf)[idx] = o;
}

__global__ __launch_bounds__(256) void dwconv(
    const float* __restrict__ Hf, const float* __restrict__ W,
    const float* __restrict__ Bv, float* __restrict__ Hc) {
    const size_t idx = (size_t)blockIdx.x * 256 + threadIdx.x;
    const int c4 = (int)(idx % (INNER / 4)) * 4;
    const int n = (int)(idx / (INNER / 4));
    float4 acc = *reinterpret_cast<const float4*>(&Bv[c4]);
#pragma unroll
    for (int k = 0; k < 3; ++k) {
        const int nn = n + k - 1;
        if (nn >= 0 && nn < N_TOK) {
            float4 x = *reinterpret_cast<const float4*>(&Hf[(size_t)nn * INNER + c4]);
            float4 w = *reinterpret_cast<const float4*>(&W[(size_t)k * INNER + c4]);
            acc.x += x.x * w.x; acc.y += x.y * w.y;
            acc.z += x.z * w.z; acc.w += x.w * w.w;
        }
    }
    acc.x = silu_f(acc.x); acc.y = silu_f(acc.y);
    acc.z = silu_f(acc.z); acc.w = silu_f(acc.w);
    *reinterpret_cast<float4*>(&Hc[(size_t)n * INNER + c4]) = acc;
}

extern "C" void kernel_launch(void* const* d_in, const int* in_sizes, int n_in,
                              void* d_out, int out_size, void* d_ws, size_t ws_size,
                              hipStream_t stream) {
    const float* Qin   = (const float*)d_in[0];
    const float* cosb  = (const float*)d_in[1];
    const float* sinb  = (const float*)d_in[2];
    const float* Wqkv  = (const float*)d_in[3];
    const float* Wo    = (const float*)d_in[4];
    const float* Wup   = (const float*)d_in[5];
    const float* convw = (const float*)d_in[6];
    const float* convb = (const float*)d_in[7];
    const float* Wdown = (const float*)d_in[8];
    float* out = (float*)d_out;
    float* ws  = (float*)d_ws;

    // workspace layout (float units)
    float* qkv = ws;                                        // 12,582,912 f
    unsigned short* Qb = (unsigned short*)(ws + 12582912);  // 4,194,304 bf16
    unsigned short* Kb = (unsigned short*)(ws + 14680064);
    unsigned short* Vt = (unsigned short*)(ws + 16777216);
    float* Vn   = ws + 18874368;                            // 4,194,304 f
    float* mcat = ws + 23068672;                            // 4,194,304 f
    float* wo_out   = ws;                                   // reuse qkv
    float* Qi       = ws + 4194304;
    float* Gbuf     = ws + 12582912;                        // reuse Qb..Vn
    float* Ubuf     = ws + 24117248;
    float* down_out = ws;

    const dim3 blk(256);
    gemm64<<<dim3(3072 / 64, 4096 / 64), blk, 0, stream>>>(
        Qin, Wqkv, qkv, 4096, 3072, 1024, 3072, 3072);
    rope_norm2<<<dim3(64, 16), blk, 0, stream>>>(qkv, cosb, sinb, Qb, Kb, Vt, Vn);
    attn_mfma<<<dim3(64, 16), blk, 0, stream>>>(Qb, Kb, Vt, Vn, mcat);
    gemm64<<<dim3(1024 / 64, 4096 / 64), blk, 0, stream>>>(
        mcat, Wo, wo_out, 4096, 1024, 1024, 1024, 1024);
    rms_resid<<<4096, blk, 0, stream>>>(wo_out, Qin, Qi);
    gemm64<<<dim3(2816 / 64, 4096 / 64), blk, 0, stream>>>(
        Qi, Wup, Gbuf, 4096, 2816, 1024, 5632, 2816);
    gemm64<<<dim3(2816 / 64, 4096 / 64), blk, 0, stream>>>(
        Qi, Wup + 2816, Ubuf, 4096, 2816, 1024, 5632, 2816);
    silu_mul<<<(4096 * (INNER / 4)) / 256, blk, 0, stream>>>(Gbuf, Ubuf, Gbuf);
    dwconv<<<(4096 * (INNER / 4)) / 256, blk, 0, stream>>>(Gbuf, convw, convb, Ubuf);
    gemm64<<<dim3(1024 / 64, 4096 / 64), blk, 0, stream>>>(
        Ubuf, Wdown, down_out, 4096, 1024, 2816, 1024, 1024);
    rms_resid<<<4096, blk, 0, stream>>>(down_out, Qi, out);
}

// Round 4
// 740.450 us; speedup vs baseline: 3.8095x; 2.7881x over previous
//
#include <hip/hip_runtime.h>
#include <hip/hip_bf16.h>
#include <cstdint>

#define N_TOK   4096
#define D_MODEL 1024
#define N_HEAD  16
#define DH      64
#define INNER   2816

typedef __attribute__((ext_vector_type(8))) short bf16x8;
typedef __attribute__((ext_vector_type(4))) float f32x4;
typedef __attribute__((ext_vector_type(8))) unsigned short us8v;
typedef __attribute__((ext_vector_type(4))) unsigned short us4v;

union BF16x8U { bf16x8 v; uint32_t u[4]; };

__device__ __forceinline__ unsigned short f2bf(float x) {
    union { __hip_bfloat16 h; unsigned short u; } c;
    c.h = __float2bfloat16(x);
    return c.u;
}

__device__ __forceinline__ float bf2f(unsigned short u) {
    union { float f; uint32_t i; } c;
    c.i = ((uint32_t)u) << 16;
    return c.f;
}

__device__ __forceinline__ float silu_f(float x) {
    return x / (1.f + __expf(-x));
}

// ---------------------------------------------------------------------------
// fp32 -> bf16 elementwise convert (8 elems/thread)
// ---------------------------------------------------------------------------
__global__ __launch_bounds__(256) void cvt_bf16(
    const float* __restrict__ in, unsigned short* __restrict__ out) {
    const size_t i8 = ((size_t)blockIdx.x * 256 + threadIdx.x) * 8;
    float4 a = *reinterpret_cast<const float4*>(&in[i8]);
    float4 b = *reinterpret_cast<const float4*>(&in[i8 + 4]);
    us8v o;
    o[0] = f2bf(a.x); o[1] = f2bf(a.y); o[2] = f2bf(a.z); o[3] = f2bf(a.w);
    o[4] = f2bf(b.x); o[5] = f2bf(b.y); o[6] = f2bf(b.z); o[7] = f2bf(b.w);
    *reinterpret_cast<us8v*>(&out[i8]) = o;
}

// ---------------------------------------------------------------------------
// W[K][N] fp32 -> WT[N][K] bf16, 64x64 LDS tile transpose.
// grid (N/64, K/64)
// ---------------------------------------------------------------------------
__global__ __launch_bounds__(256) void transpose_bf16(
    const float* __restrict__ W, unsigned short* __restrict__ WT,
    int K, int N) {
    __shared__ unsigned short T[64][65];
    const int n0 = blockIdx.x * 64;
    const int k0 = blockIdx.y * 64;
    const int t = threadIdx.x;
#pragma unroll
    for (int i = 0; i < 4; ++i) {
        const int id = i * 256 + t;
        const int r = id >> 4;          // k row 0..63
        const int c = (id & 15) * 4;    // n col
        float4 v = *reinterpret_cast<const float4*>(
            &W[(size_t)(k0 + r) * N + n0 + c]);
        T[c + 0][r] = f2bf(v.x);
        T[c + 1][r] = f2bf(v.y);
        T[c + 2][r] = f2bf(v.z);
        T[c + 3][r] = f2bf(v.w);
    }
    __syncthreads();
#pragma unroll
    for (int i = 0; i < 2; ++i) {
        const int id = i * 256 + t;
        const int n = id >> 3;          // 0..63
        const int c = (id & 7) * 8;     // k chunk
        us8v o;
#pragma unroll
        for (int j = 0; j < 8; ++j) o[j] = T[n][c + j];
        *reinterpret_cast<us8v*>(&WT[(size_t)(n0 + n) * K + k0 + c]) = o;
    }
}

// ---------------------------------------------------------------------------
// bf16 MFMA GEMM: C[M][N] = A[M][K] @ Bt[N][K]^T.
// 128x128 tile, BK=64, 4 waves (2x2), 16x16x32 MFMA, reg-staged LDS with
// rows padded to 72 shorts (2-way banks = free). OBF: 1 -> bf16 C, 0 -> fp32.
// grid (N/128, M/128). K % 64 == 0.
// ---------------------------------------------------------------------------
template<int OBF>
__global__ __launch_bounds__(256) void gemm_bf16(
    const unsigned short* __restrict__ A, const unsigned short* __restrict__ Bt,
    void* __restrict__ Cout, int M, int N, int K) {
    __shared__ unsigned short As[128 * 72];
    __shared__ unsigned short Bs[128 * 72];
    const int tid = threadIdx.x;
    const int lane = tid & 63;
    const int w = tid >> 6;
    const int l15 = lane & 15, lg = lane >> 4;
    const int wm = w >> 1, wn = w & 1;
    const int rowBase = blockIdx.y * 128;
    const int colBase = blockIdx.x * 128;

    f32x4 acc[4][4];
#pragma unroll
    for (int i = 0; i < 4; ++i)
#pragma unroll
        for (int j = 0; j < 4; ++j) acc[i][j] = (f32x4){0.f, 0.f, 0.f, 0.f};

    for (int k0 = 0; k0 < K; k0 += 64) {
        us8v a_r[4], b_r[4];
#pragma unroll
        for (int i = 0; i < 4; ++i) {
            const int ch = i * 256 + tid;
            const int r = ch >> 3, c = (ch & 7) * 8;
            a_r[i] = *reinterpret_cast<const us8v*>(
                &A[(size_t)(rowBase + r) * K + k0 + c]);
            b_r[i] = *reinterpret_cast<const us8v*>(
                &Bt[(size_t)(colBase + r) * K + k0 + c]);
        }
        __syncthreads();
#pragma unroll
        for (int i = 0; i < 4; ++i) {
            const int ch = i * 256 + tid;
            const int r = ch >> 3, c = (ch & 7) * 8;
            *reinterpret_cast<us8v*>(&As[r * 72 + c]) = a_r[i];
            *reinterpret_cast<us8v*>(&Bs[r * 72 + c]) = b_r[i];
        }
        __syncthreads();
        bf16x8 af[2][4], bfr[2][4];
#pragma unroll
        for (int kk = 0; kk < 2; ++kk) {
#pragma unroll
            for (int f = 0; f < 4; ++f) {
                af[kk][f] = *reinterpret_cast<const bf16x8*>(
                    &As[(wm * 64 + f * 16 + l15) * 72 + kk * 32 + lg * 8]);
                bfr[kk][f] = *reinterpret_cast<const bf16x8*>(
                    &Bs[(wn * 64 + f * 16 + l15) * 72 + kk * 32 + lg * 8]);
            }
        }
#pragma unroll
        for (int kk = 0; kk < 2; ++kk)
#pragma unroll
            for (int mf = 0; mf < 4; ++mf)
#pragma unroll
                for (int nf = 0; nf < 4; ++nf)
                    acc[mf][nf] = __builtin_amdgcn_mfma_f32_16x16x32_bf16(
                        bfr[kk][nf], af[kk][mf], acc[mf][nf], 0, 0, 0);
    }
    // epilogue: lane l15 = m row within tile, lg*4+r = n col within tile
#pragma unroll
    for (int mf = 0; mf < 4; ++mf) {
#pragma unroll
        for (int nf = 0; nf < 4; ++nf) {
            const size_t m = rowBase + wm * 64 + mf * 16 + l15;
            const size_t n = colBase + wn * 64 + nf * 16 + lg * 4;
            if (OBF) {
                us4v o;
                o[0] = f2bf(acc[mf][nf][0]); o[1] = f2bf(acc[mf][nf][1]);
                o[2] = f2bf(acc[mf][nf][2]); o[3] = f2bf(acc[mf][nf][3]);
                *reinterpret_cast<us4v*>(
                    &((unsigned short*)Cout)[m * N + n]) = o;
            } else {
                float4 o;
                o.x = acc[mf][nf][0]; o.y = acc[mf][nf][1];
                o.z = acc[mf][nf][2]; o.w = acc[mf][nf][3];
                *reinterpret_cast<float4*>(&((float*)Cout)[m * N + n]) = o;
            }
        }
    }
}

// ---------------------------------------------------------------------------
// RoPE + RMS-norm; emits Qb,Kb [h][n][d] bf16, Vt [h][d][n] bf16 (LDS
// transpose), Vb [h][n][d] bf16. Block = (64-token chunk, head).
// ---------------------------------------------------------------------------
__global__ __launch_bounds__(256) void rope_norm2(
    const float* __restrict__ qkv, const float* __restrict__ cosb,
    const float* __restrict__ sinb, unsigned short* __restrict__ Qb,
    unsigned short* __restrict__ Kb, unsigned short* __restrict__ Vt,
    unsigned short* __restrict__ Vb) {
    const int h = blockIdx.y;
    const int n0 = blockIdx.x * 64;
    const int wv = threadIdx.x >> 6;
    const int lane = threadIdx.x & 63;
    __shared__ unsigned short Vs[64][66];
#pragma unroll 1
    for (int it = 0; it < 16; ++it) {
        const int tn = it * 4 + wv;
        const int n = n0 + tn;
        const float* base = qkv + (size_t)n * (3 * D_MODEL) + h * DH;
        float qv = base[lane];
        float kv = base[D_MODEL + lane];
        float vv = base[2 * D_MODEL + lane];
        const float c = cosb[n * DH + lane];
        const float s = sinb[n * DH + lane];
        const float qp = __shfl(qv, lane ^ 32, 64);
        const float kp = __shfl(kv, lane ^ 32, 64);
        const float sgn = (lane < 32) ? -1.f : 1.f;
        qv = qv * c + sgn * qp * s;
        kv = kv * c + sgn * kp * s;
        float sq = qv * qv, sk = kv * kv;
#pragma unroll
        for (int off = 32; off > 0; off >>= 1) {
            sq += __shfl_xor(sq, off, 64);
            sk += __shfl_xor(sk, off, 64);
        }
        qv *= rsqrtf(sq * (1.f / DH) + 1e-5f);
        kv *= rsqrtf(sk * (1.f / DH) + 1e-5f);
        const size_t o = ((size_t)h * N_TOK + n) * DH + lane;
        Qb[o] = f2bf(qv);
        Kb[o] = f2bf(kv);
        Vb[o] = f2bf(vv);
        Vs[tn][lane] = f2bf(vv);
    }
    __syncthreads();
    const int d = threadIdx.x >> 2;
    const int c0 = (threadIdx.x & 3) * 16;
    us8v o0, o1;
#pragma unroll
    for (int i = 0; i < 8; ++i) o0[i] = Vs[c0 + i][d];
#pragma unroll
    for (int i = 0; i < 8; ++i) o1[i] = Vs[c0 + 8 + i][d];
    unsigned short* dst = Vt + ((size_t)h * DH + d) * N_TOK + n0 + c0;
    *reinterpret_cast<us8v*>(dst) = o0;
    *reinterpret_cast<us8v*>(dst + 8) = o1;
}

// ---------------------------------------------------------------------------
// MFMA linear attention (structure unchanged from round 2; V read bf16,
// m_concat written bf16).
// ---------------------------------------------------------------------------
__global__ __launch_bounds__(256) void attn_mfma(
    const unsigned short* __restrict__ Qb, const unsigned short* __restrict__ Kb,
    const unsigned short* __restrict__ Vt, const unsigned short* __restrict__ Vb,
    unsigned short* __restrict__ Mout) {
    const int h = blockIdx.y;
    const int q0 = blockIdx.x * 64;
    const int lane = threadIdx.x & 63;
    const int wv = threadIdx.x >> 6;
    const int l15 = lane & 15, lg = lane >> 4;
    const int qw = q0 + wv * 16;
    const unsigned short* Qh = Qb + (size_t)h * N_TOK * DH;
    const unsigned short* Kh = Kb + (size_t)h * N_TOK * DH;
    const unsigned short* Vth = Vt + (size_t)h * DH * N_TOK;

    const bf16x8 qf0 = *reinterpret_cast<const bf16x8*>(
        Qh + (size_t)(qw + l15) * DH + lg * 8);
    const bf16x8 qf1 = *reinterpret_cast<const bf16x8*>(
        Qh + (size_t)(qw + l15) * DH + 32 + lg * 8);

    f32x4 ct[4];
#pragma unroll
    for (int i = 0; i < 4; ++i) ct[i] = (f32x4){0.f, 0.f, 0.f, 0.f};
    float dpart = 0.f;

    for (int k0 = 0; k0 < N_TOK; k0 += 64) {
        const unsigned short* kp = Kh + (size_t)(k0 + l15) * DH + lg * 8;
        bf16x8 kf[4][2];
#pragma unroll
        for (int ks = 0; ks < 4; ++ks) {
            kf[ks][0] = *reinterpret_cast<const bf16x8*>(kp + ks * 16 * DH);
            kf[ks][1] = *reinterpret_cast<const bf16x8*>(kp + ks * 16 * DH + 32);
        }
        const unsigned short* vp = Vth + (size_t)l15 * N_TOK + k0 + lg * 8;
        bf16x8 vf[4][2];
#pragma unroll
        for (int ds = 0; ds < 4; ++ds) {
            vf[ds][0] = *reinterpret_cast<const bf16x8*>(vp + (size_t)ds * 16 * N_TOK);
            vf[ds][1] = *reinterpret_cast<const bf16x8*>(vp + (size_t)ds * 16 * N_TOK + 32);
        }
        f32x4 st[4];
#pragma unroll
        for (int ks = 0; ks < 4; ++ks) {
            f32x4 z = (f32x4){0.f, 0.f, 0.f, 0.f};
            z = __builtin_amdgcn_mfma_f32_16x16x32_bf16(kf[ks][0], qf0, z, 0, 0, 0);
            st[ks] = __builtin_amdgcn_mfma_f32_16x16x32_bf16(kf[ks][1], qf1, st[ks] = z, 0, 0, 0);
        }
        uint32_t wpk[4][2];
#pragma unroll
        for (int ks = 0; ks < 4; ++ks) {
            float wv4[4];
#pragma unroll
            for (int r = 0; r < 4; ++r) {
                const float x = st[ks][r] * 0.125f;
                float e = fmaxf(x, 0.f) + __expf(fminf(x, 0.f));
                e = e * e;
                wv4[r] = e;
                dpart += e;
            }
            wpk[ks][0] = (uint32_t)f2bf(wv4[0]) | ((uint32_t)f2bf(wv4[1]) << 16);
            wpk[ks][1] = (uint32_t)f2bf(wv4[2]) | ((uint32_t)f2bf(wv4[3]) << 16);
        }
        const int sA = l15 + ((lg & 1) << 5);
        const int sB = sA + 16;
        const bool hi = (lg & 2) != 0;
#pragma unroll
        for (int kh = 0; kh < 2; ++kh) {
            const uint32_t a0 = (uint32_t)__shfl((int)wpk[2 * kh][0], sA, 64);
            const uint32_t a1 = (uint32_t)__shfl((int)wpk[2 * kh][1], sA, 64);
            const uint32_t a2 = (uint32_t)__shfl((int)wpk[2 * kh][0], sB, 64);
            const uint32_t a3 = (uint32_t)__shfl((int)wpk[2 * kh][1], sB, 64);
            const uint32_t b0 = (uint32_t)__shfl((int)wpk[2 * kh + 1][0], sA, 64);
            const uint32_t b1 = (uint32_t)__shfl((int)wpk[2 * kh + 1][1], sA, 64);
            const uint32_t b2 = (uint32_t)__shfl((int)wpk[2 * kh + 1][0], sB, 64);
            const uint32_t b3 = (uint32_t)__shfl((int)wpk[2 * kh + 1][1], sB, 64);
            BF16x8U bb;
            bb.u[0] = hi ? b0 : a0;
            bb.u[1] = hi ? b1 : a1;
            bb.u[2] = hi ? b2 : a2;
            bb.u[3] = hi ? b3 : a3;
#pragma unroll
            for (int ds = 0; ds < 4; ++ds)
                ct[ds] = __builtin_amdgcn_mfma_f32_16x16x32_bf16(
                    vf[ds][kh], bb.v, ct[ds], 0, 0, 0);
        }
    }
    dpart += __shfl_xor(dpart, 16, 64);
    dpart += __shfl_xor(dpart, 32, 64);
    const float dn = 1.f / (dpart + 1e-6f);
    const unsigned short* Vh = Vb + (size_t)h * N_TOK * DH;
    const int q = qw + l15;
#pragma unroll
    for (int ds = 0; ds < 4; ++ds) {
        const int d = ds * 16 + lg * 4;
        const us4v vv = *reinterpret_cast<const us4v*>(&Vh[(size_t)q * DH + d]);
        us4v o;
        o[0] = f2bf(ct[ds][0] * dn - bf2f(vv[0]));
        o[1] = f2bf(ct[ds][1] * dn - bf2f(vv[1]));
        o[2] = f2bf(ct[ds][2] * dn - bf2f(vv[2]));
        o[3] = f2bf(ct[ds][3] * dn - bf2f(vv[3]));
        *reinterpret_cast<us4v*>(&Mout[(size_t)q * D_MODEL + h * DH + d]) = o;
    }
}

// ---------------------------------------------------------------------------
// O = rmsnorm(X + R); fp32 out always, bf16 out if WB.
// ---------------------------------------------------------------------------
template<int WB>
__global__ __launch_bounds__(256) void rms_resid2(
    const float* __restrict__ X, const float* __restrict__ R,
    float* __restrict__ O32, unsigned short* __restrict__ Obf) {
    const int row = blockIdx.x;
    const int tid = threadIdx.x;
    const float4 xv = reinterpret_cast<const float4*>(X + (size_t)row * D_MODEL)[tid];
    const float4 rv = reinterpret_cast<const float4*>(R + (size_t)row * D_MODEL)[tid];
    const float t0 = xv.x + rv.x, t1 = xv.y + rv.y, t2 = xv.z + rv.z, t3 = xv.w + rv.w;
    float ss = t0 * t0 + t1 * t1 + t2 * t2 + t3 * t3;
#pragma unroll
    for (int off = 32; off > 0; off >>= 1) ss += __shfl_xor(ss, off, 64);
    __shared__ float red[4];
    if ((tid & 63) == 0) red[tid >> 6] = ss;
    __syncthreads();
    const float tot = red[0] + red[1] + red[2] + red[3];
    const float rs = rsqrtf(tot * (1.f / D_MODEL) + 1e-5f);
    float4 o;
    o.x = t0 * rs; o.y = t1 * rs; o.z = t2 * rs; o.w = t3 * rs;
    reinterpret_cast<float4*>(O32 + (size_t)row * D_MODEL)[tid] = o;
    if (WB) {
        us4v ob;
        ob[0] = f2bf(o.x); ob[1] = f2bf(o.y); ob[2] = f2bf(o.z); ob[3] = f2bf(o.w);
        *reinterpret_cast<us4v*>(&Obf[(size_t)row * D_MODEL + tid * 4]) = ob;
    }
}

// Hf = silu(G)*U from GU bf16 [4096][5632]; out bf16 [4096][2816]
__global__ __launch_bounds__(256) void silu_mul_bf(
    const unsigned short* __restrict__ GU, unsigned short* __restrict__ Hf) {
    const size_t idx = (size_t)blockIdx.x * 256 + threadIdx.x;
    const int c8 = (int)(idx % (INNER / 8)) * 8;
    const int n = (int)(idx / (INNER / 8));
    us8v g = *reinterpret_cast<const us8v*>(&GU[(size_t)n * (2 * INNER) + c8]);
    us8v u = *reinterpret_cast<const us8v*>(&GU[(size_t)n * (2 * INNER) + INNER + c8]);
    us8v o;
#pragma unroll
    for (int j = 0; j < 8; ++j) {
        const float gv = bf2f(g[j]);
        o[j] = f2bf(silu_f(gv) * bf2f(u[j]));
    }
    *reinterpret_cast<us8v*>(&Hf[(size_t)n * INNER + c8]) = o;
}

// depthwise conv k=3 pad=1 + bias + silu; bf16 in/out, fp32 math
__global__ __launch_bounds__(256) void dwconv_bf(
    const unsigned short* __restrict__ Hf, const float* __restrict__ W,
    const float* __restrict__ Bv, unsigned short* __restrict__ Hc) {
    const size_t idx = (size_t)blockIdx.x * 256 + threadIdx.x;
    const int c8 = (int)(idx % (INNER / 8)) * 8;
    const int n = (int)(idx / (INNER / 8));
    float a[8];
    {
        float4 b0 = *reinterpret_cast<const float4*>(&Bv[c8]);
        float4 b1 = *reinterpret_cast<const float4*>(&Bv[c8 + 4]);
        a[0] = b0.x; a[1] = b0.y; a[2] = b0.z; a[3] = b0.w;
        a[4] = b1.x; a[5] = b1.y; a[6] = b1.z; a[7] = b1.w;
    }
#pragma unroll
    for (int k = 0; k < 3; ++k) {
        const int nn = n + k - 1;
        if (nn >= 0 && nn < N_TOK) {
            us8v x = *reinterpret_cast<const us8v*>(&Hf[(size_t)nn * INNER + c8]);
            float4 w0 = *reinterpret_cast<const float4*>(&W[(size_t)k * INNER + c8]);
            float4 w1 = *reinterpret_cast<const float4*>(&W[(size_t)k * INNER + c8 + 4]);
            a[0] += bf2f(x[0]) * w0.x; a[1] += bf2f(x[1]) * w0.y;
            a[2] += bf2f(x[2]) * w0.z; a[3] += bf2f(x[3]) * w0.w;
            a[4] += bf2f(x[4]) * w1.x; a[5] += bf2f(x[5]) * w1.y;
            a[6] += bf2f(x[6]) * w1.z; a[7] += bf2f(x[7]) * w1.w;
        }
    }
    us8v o;
#pragma unroll
    for (int j = 0; j < 8; ++j) o[j] = f2bf(silu_f(a[j]));
    *reinterpret_cast<us8v*>(&Hc[(size_t)n * INNER + c8]) = o;
}

extern "C" void kernel_launch(void* const* d_in, const int* in_sizes, int n_in,
                              void* d_out, int out_size, void* d_ws, size_t ws_size,
                              hipStream_t stream) {
    const float* Qin   = (const float*)d_in[0];
    const float* cosb  = (const float*)d_in[1];
    const float* sinb  = (const float*)d_in[2];
    const float* Wqkv  = (const float*)d_in[3];
    const float* Wo    = (const float*)d_in[4];
    const float* Wup   = (const float*)d_in[5];
    const float* convw = (const float*)d_in[6];
    const float* convb = (const float*)d_in[7];
    const float* Wdown = (const float*)d_in[8];
    float* out = (float*)d_out;
    float* ws  = (float*)d_ws;

    // ---- workspace layout (float-unit offsets; peak 34,734,080 f = 139 MB)
    unsigned short* WqkvT  = (unsigned short*)(ws);              // [3072][1024]
    unsigned short* WoT    = (unsigned short*)(ws + 1572864);    // [1024][1024]
    unsigned short* WupT   = (unsigned short*)(ws + 2097152);    // [5632][1024]
    unsigned short* WdownT = (unsigned short*)(ws + 4980736);    // [1024][2816]
    unsigned short* Qin_bf = (unsigned short*)(ws + 6422528);    // [4096][1024]
    unsigned short* mcat   = (unsigned short*)(ws + 6422528);    // reuse (after GEMM1)
    float*          qkv32  = ws + 8519680;                       // [4096][3072]
    float*          wo32   = ws + 8519680;                       // reuse (after rope)
    unsigned short* GU     = (unsigned short*)(ws + 8519680);    // [4096][5632] (after rms)
    unsigned short* Hc     = (unsigned short*)(ws + 8519680);    // [4096][2816] (after silu+conv)
    float*          dn32   = ws + 14286848;                      // [4096][1024]
    unsigned short* Qb     = (unsigned short*)(ws + 21102592);
    unsigned short* Kb     = (unsigned short*)(ws + 23199744);
    unsigned short* Vt     = (unsigned short*)(ws + 25296896);
    unsigned short* Vb     = (unsigned short*)(ws + 27394048);
    unsigned short* Hf     = (unsigned short*)(ws + 21102592);   // reuse (after attn)
    float*          Qi32   = ws + 29491200;                      // [4096][1024]
    unsigned short* Qi_bf  = (unsigned short*)(ws + 33685504);   // [4096][1024]

    const dim3 blk(256);
    // 0. weight / input prep
    cvt_bf16<<<2048, blk, 0, stream>>>(Qin, Qin_bf);
    transpose_bf16<<<dim3(48, 16), blk, 0, stream>>>(Wqkv, WqkvT, 1024, 3072);
    transpose_bf16<<<dim3(16, 16), blk, 0, stream>>>(Wo, WoT, 1024, 1024);
    transpose_bf16<<<dim3(88, 16), blk, 0, stream>>>(Wup, WupT, 1024, 5632);
    transpose_bf16<<<dim3(16, 44), blk, 0, stream>>>(Wdown, WdownT, 2816, 1024);
    // 1. QKV projection (fp32 out for RoPE/RMS precision)
    gemm_bf16<0><<<dim3(24, 32), blk, 0, stream>>>(
        Qin_bf, WqkvT, qkv32, 4096, 3072, 1024);
    // 2. RoPE + RMS + transposes
    rope_norm2<<<dim3(64, 16), blk, 0, stream>>>(qkv32, cosb, sinb, Qb, Kb, Vt, Vb);
    // 3. attention -> m_concat (bf16)
    attn_mfma<<<dim3(64, 16), blk, 0, stream>>>(Qb, Kb, Vt, Vb, mcat);
    // 4. W_o projection (fp32 out)
    gemm_bf16<0><<<dim3(8, 32), blk, 0, stream>>>(
        mcat, WoT, wo32, 4096, 1024, 1024);
    // 5. Q_interact = rmsnorm(Q_in + wo_out) -> fp32 + bf16
    rms_resid2<1><<<4096, blk, 0, stream>>>(wo32, Qin, Qi32, Qi_bf);
    // 6. GU = Qi @ Wup (bf16 out)
    gemm_bf16<1><<<dim3(44, 32), blk, 0, stream>>>(
        Qi_bf, WupT, GU, 4096, 5632, 1024);
    // 7. Hf = silu(G)*U
    silu_mul_bf<<<5632, blk, 0, stream>>>(GU, Hf);
    // 8. depthwise conv + bias + silu
    dwconv_bf<<<5632, blk, 0, stream>>>(Hf, convw, convb, Hc);
    // 9. W_down projection (fp32 out)
    gemm_bf16<0><<<dim3(8, 32), blk, 0, stream>>>(
        Hc, WdownT, dn32, 4096, 1024, 2816);
    // 10. out = rmsnorm(Qi + dn)
    rms_resid2<0><<<4096, blk, 0, stream>>>(dn32, Qi32, out, nullptr);
}

// Round 6
// 461.122 us; speedup vs baseline: 6.1171x; 1.6058x over previous
//
#include <hip/hip_runtime.h>
#include <hip/hip_bf16.h>
#include <cstdint>

#define N_TOK   4096
#define D_MODEL 1024
#define N_HEAD  16
#define DH      64
#define INNER   2816

typedef __attribute__((ext_vector_type(8))) short bf16x8;
typedef __attribute__((ext_vector_type(4))) float f32x4;
typedef __attribute__((ext_vector_type(8))) unsigned short us8v;
typedef __attribute__((ext_vector_type(4))) unsigned short us4v;

union BF16x8U { bf16x8 v; uint32_t u[4]; };

__device__ __forceinline__ unsigned short f2bf(float x) {
    union { __hip_bfloat16 h; unsigned short u; } c;
    c.h = __float2bfloat16(x);
    return c.u;
}

__device__ __forceinline__ float bf2f(unsigned short u) {
    union { float f; uint32_t i; } c;
    c.i = ((uint32_t)u) << 16;
    return c.f;
}

__device__ __forceinline__ float silu_f(float x) {
    return x / (1.f + __expf(-x));
}

// ---------------------------------------------------------------------------
// fp32 -> bf16 elementwise convert (8 elems/thread)
// ---------------------------------------------------------------------------
__global__ __launch_bounds__(256) void cvt_bf16(
    const float* __restrict__ in, unsigned short* __restrict__ out) {
    const size_t i8 = ((size_t)blockIdx.x * 256 + threadIdx.x) * 8;
    float4 a = *reinterpret_cast<const float4*>(&in[i8]);
    float4 b = *reinterpret_cast<const float4*>(&in[i8 + 4]);
    us8v o;
    o[0] = f2bf(a.x); o[1] = f2bf(a.y); o[2] = f2bf(a.z); o[3] = f2bf(a.w);
    o[4] = f2bf(b.x); o[5] = f2bf(b.y); o[6] = f2bf(b.z); o[7] = f2bf(b.w);
    *reinterpret_cast<us8v*>(&out[i8]) = o;
}

// ---------------------------------------------------------------------------
// W[K][N] fp32 -> WT[N][K] bf16, 64x64 LDS tile transpose. grid (N/64, K/64)
// ---------------------------------------------------------------------------
__global__ __launch_bounds__(256) void transpose_bf16(
    const float* __restrict__ W, unsigned short* __restrict__ WT,
    int K, int N) {
    __shared__ unsigned short T[64][65];
    const int n0 = blockIdx.x * 64;
    const int k0 = blockIdx.y * 64;
    const int t = threadIdx.x;
#pragma unroll
    for (int i = 0; i < 4; ++i) {
        const int id = i * 256 + t;
        const int r = id >> 4;
        const int c = (id & 15) * 4;
        float4 v = *reinterpret_cast<const float4*>(
            &W[(size_t)(k0 + r) * N + n0 + c]);
        T[c + 0][r] = f2bf(v.x);
        T[c + 1][r] = f2bf(v.y);
        T[c + 2][r] = f2bf(v.z);
        T[c + 3][r] = f2bf(v.w);
    }
    __syncthreads();
#pragma unroll
    for (int i = 0; i < 2; ++i) {
        const int id = i * 256 + t;
        const int n = id >> 3;
        const int c = (id & 7) * 8;
        us8v o;
#pragma unroll
        for (int j = 0; j < 8; ++j) o[j] = T[n][c + j];
        *reinterpret_cast<us8v*>(&WT[(size_t)(n0 + n) * K + k0 + c]) = o;
    }
}

// ---------------------------------------------------------------------------
// bf16 MFMA GEMM: C[M][N] = A[M][K] @ Bt[N][K]^T. 128x128 tile, BK=64,
// 4 waves, 16x16x32 MFMA, LDS rows padded to 72. OBF: 1 -> bf16 C, 0 -> fp32.
// ---------------------------------------------------------------------------
template<int OBF>
__global__ __launch_bounds__(256) void gemm_bf16(
    const unsigned short* __restrict__ A, const unsigned short* __restrict__ Bt,
    void* __restrict__ Cout, int M, int N, int K) {
    __shared__ unsigned short As[128 * 72];
    __shared__ unsigned short Bs[128 * 72];
    const int tid = threadIdx.x;
    const int lane = tid & 63;
    const int w = tid >> 6;
    const int l15 = lane & 15, lg = lane >> 4;
    const int wm = w >> 1, wn = w & 1;
    const int rowBase = blockIdx.y * 128;
    const int colBase = blockIdx.x * 128;

    f32x4 acc[4][4];
#pragma unroll
    for (int i = 0; i < 4; ++i)
#pragma unroll
        for (int j = 0; j < 4; ++j) acc[i][j] = (f32x4){0.f, 0.f, 0.f, 0.f};

    for (int k0 = 0; k0 < K; k0 += 64) {
        us8v a_r[4], b_r[4];
#pragma unroll
        for (int i = 0; i < 4; ++i) {
            const int ch = i * 256 + tid;
            const int r = ch >> 3, c = (ch & 7) * 8;
            a_r[i] = *reinterpret_cast<const us8v*>(
                &A[(size_t)(rowBase + r) * K + k0 + c]);
            b_r[i] = *reinterpret_cast<const us8v*>(
                &Bt[(size_t)(colBase + r) * K + k0 + c]);
        }
        __syncthreads();
#pragma unroll
        for (int i = 0; i < 4; ++i) {
            const int ch = i * 256 + tid;
            const int r = ch >> 3, c = (ch & 7) * 8;
            *reinterpret_cast<us8v*>(&As[r * 72 + c]) = a_r[i];
            *reinterpret_cast<us8v*>(&Bs[r * 72 + c]) = b_r[i];
        }
        __syncthreads();
        bf16x8 af[2][4], bfr[2][4];
#pragma unroll
        for (int kk = 0; kk < 2; ++kk) {
#pragma unroll
            for (int f = 0; f < 4; ++f) {
                af[kk][f] = *reinterpret_cast<const bf16x8*>(
                    &As[(wm * 64 + f * 16 + l15) * 72 + kk * 32 + lg * 8]);
                bfr[kk][f] = *reinterpret_cast<const bf16x8*>(
                    &Bs[(wn * 64 + f * 16 + l15) * 72 + kk * 32 + lg * 8]);
            }
        }
#pragma unroll
        for (int kk = 0; kk < 2; ++kk)
#pragma unroll
            for (int mf = 0; mf < 4; ++mf)
#pragma unroll
                for (int nf = 0; nf < 4; ++nf)
                    acc[mf][nf] = __builtin_amdgcn_mfma_f32_16x16x32_bf16(
                        bfr[kk][nf], af[kk][mf], acc[mf][nf], 0, 0, 0);
    }
#pragma unroll
    for (int mf = 0; mf < 4; ++mf) {
#pragma unroll
        for (int nf = 0; nf < 4; ++nf) {
            const size_t m = rowBase + wm * 64 + mf * 16 + l15;
            const size_t n = colBase + wn * 64 + nf * 16 + lg * 4;
            if (OBF) {
                us4v o;
                o[0] = f2bf(acc[mf][nf][0]); o[1] = f2bf(acc[mf][nf][1]);
                o[2] = f2bf(acc[mf][nf][2]); o[3] = f2bf(acc[mf][nf][3]);
                *reinterpret_cast<us4v*>(
                    &((unsigned short*)Cout)[m * N + n]) = o;
            } else {
                float4 o;
                o.x = acc[mf][nf][0]; o.y = acc[mf][nf][1];
                o.z = acc[mf][nf][2]; o.w = acc[mf][nf][3];
                *reinterpret_cast<float4*>(&((float*)Cout)[m * N + n]) = o;
            }
        }
    }
}

// ---------------------------------------------------------------------------
// RoPE + RMS-norm; emits Qb,Kb [h][n][d] bf16, Vt [h][d][n] bf16, Vb bf16.
// ---------------------------------------------------------------------------
__global__ __launch_bounds__(256) void rope_norm2(
    const float* __restrict__ qkv, const float* __restrict__ cosb,
    const float* __restrict__ sinb, unsigned short* __restrict__ Qb,
    unsigned short* __restrict__ Kb, unsigned short* __restrict__ Vt,
    unsigned short* __restrict__ Vb) {
    const int h = blockIdx.y;
    const int n0 = blockIdx.x * 64;
    const int wv = threadIdx.x >> 6;
    const int lane = threadIdx.x & 63;
    __shared__ unsigned short Vs[64][66];
#pragma unroll 1
    for (int it = 0; it < 16; ++it) {
        const int tn = it * 4 + wv;
        const int n = n0 + tn;
        const float* base = qkv + (size_t)n * (3 * D_MODEL) + h * DH;
        float qv = base[lane];
        float kv = base[D_MODEL + lane];
        float vv = base[2 * D_MODEL + lane];
        const float c = cosb[n * DH + lane];
        const float s = sinb[n * DH + lane];
        const float qp = __shfl(qv, lane ^ 32, 64);
        const float kp = __shfl(kv, lane ^ 32, 64);
        const float sgn = (lane < 32) ? -1.f : 1.f;
        qv = qv * c + sgn * qp * s;
        kv = kv * c + sgn * kp * s;
        float sq = qv * qv, sk = kv * kv;
#pragma unroll
        for (int off = 32; off > 0; off >>= 1) {
            sq += __shfl_xor(sq, off, 64);
            sk += __shfl_xor(sk, off, 64);
        }
        qv *= rsqrtf(sq * (1.f / DH) + 1e-5f);
        kv *= rsqrtf(sk * (1.f / DH) + 1e-5f);
        const size_t o = ((size_t)h * N_TOK + n) * DH + lane;
        Qb[o] = f2bf(qv);
        Kb[o] = f2bf(kv);
        Vb[o] = f2bf(vv);
        Vs[tn][lane] = f2bf(vv);
    }
    __syncthreads();
    const int d = threadIdx.x >> 2;
    const int c0 = (threadIdx.x & 3) * 16;
    us8v o0, o1;
#pragma unroll
    for (int i = 0; i < 8; ++i) o0[i] = Vs[c0 + i][d];
#pragma unroll
    for (int i = 0; i < 8; ++i) o1[i] = Vs[c0 + 8 + i][d];
    unsigned short* dst = Vt + ((size_t)h * DH + d) * N_TOK + n0 + c0;
    *reinterpret_cast<us8v*>(dst) = o0;
    *reinterpret_cast<us8v*>(dst + 8) = o1;
}

// ---------------------------------------------------------------------------
// MFMA linear attention v2: k-split across waves.
// Block = 64 queries x 1 head, 4 waves. Wave wv processes keys
// [wv*1024, (wv+1)*1024) for ALL 64 queries (4 q-subtiles of 16) -> zero
// intra-block load redundancy. XCD-clustered decode: head h -> XCD h>>1, so
// each XCD's K/V working set is 2 heads (2 MB, L2-resident).
// Cross-wave reduce of acc/denom via LDS at the end.
// ---------------------------------------------------------------------------
__global__ __launch_bounds__(256, 2) void attn_mfma2(
    const unsigned short* __restrict__ Qb, const unsigned short* __restrict__ Kb,
    const unsigned short* __restrict__ Vt, const unsigned short* __restrict__ Vb,
    unsigned short* __restrict__ Mout) {
    // decode: B = blockIdx.x in [0,1024); xcd = B&7 (HW round-robin),
    // head = (B&7)*2 + ((B>>3)&1), qtile = B>>4.
    const int B = blockIdx.x;
    const int h = ((B & 7) << 1) | ((B >> 3) & 1);
    const int q0 = (B >> 4) * 64;
    const int lane = threadIdx.x & 63;
    const int wv = threadIdx.x >> 6;
    const int l15 = lane & 15, lg = lane >> 4;
    const unsigned short* Qh = Qb + (size_t)h * N_TOK * DH;
    const unsigned short* Kh = Kb + (size_t)h * N_TOK * DH;
    const unsigned short* Vth = Vt + (size_t)h * DH * N_TOK;

    // Q fragments for all 4 q-subtiles
    bf16x8 qf[4][2];
#pragma unroll
    for (int qs = 0; qs < 4; ++qs) {
        const unsigned short* qp = Qh + (size_t)(q0 + qs * 16 + l15) * DH + lg * 8;
        qf[qs][0] = *reinterpret_cast<const bf16x8*>(qp);
        qf[qs][1] = *reinterpret_cast<const bf16x8*>(qp + 32);
    }

    f32x4 ct[4][4];   // [qsub][ds]
#pragma unroll
    for (int i = 0; i < 4; ++i)
#pragma unroll
        for (int j = 0; j < 4; ++j) ct[i][j] = (f32x4){0.f, 0.f, 0.f, 0.f};
    float dpart[4] = {0.f, 0.f, 0.f, 0.f};

    const int sA = l15 + ((lg & 1) << 5);
    const int sB = sA + 16;
    const bool hi = (lg & 2) != 0;

#pragma unroll 1
    for (int kt = 0; kt < 16; ++kt) {
        const int k0 = (wv * 16 + kt) * 64;
        const unsigned short* kp = Kh + (size_t)(k0 + l15) * DH + lg * 8;
        bf16x8 kf[4][2];
#pragma unroll
        for (int ks = 0; ks < 4; ++ks) {
            kf[ks][0] = *reinterpret_cast<const bf16x8*>(kp + ks * 16 * DH);
            kf[ks][1] = *reinterpret_cast<const bf16x8*>(kp + ks * 16 * DH + 32);
        }
        const unsigned short* vp = Vth + (size_t)l15 * N_TOK + k0 + lg * 8;
        bf16x8 vf[4][2];
#pragma unroll
        for (int ds = 0; ds < 4; ++ds) {
            vf[ds][0] = *reinterpret_cast<const bf16x8*>(vp + (size_t)ds * 16 * N_TOK);
            vf[ds][1] = *reinterpret_cast<const bf16x8*>(vp + (size_t)ds * 16 * N_TOK + 32);
        }
#pragma unroll
        for (int qs = 0; qs < 4; ++qs) {
            // S^T subtiles: lane holds S^T[k=ks*16+lg*4+r][q=q0+qs*16+l15]
            f32x4 st[4];
#pragma unroll
            for (int ks = 0; ks < 4; ++ks) {
                f32x4 z = (f32x4){0.f, 0.f, 0.f, 0.f};
                z = __builtin_amdgcn_mfma_f32_16x16x32_bf16(kf[ks][0], qf[qs][0], z, 0, 0, 0);
                st[ks] = __builtin_amdgcn_mfma_f32_16x16x32_bf16(kf[ks][1], qf[qs][1], z, 0, 0, 0);
            }
            // W = (elu(s/8)+1)^2, per-lane denom partial, pack bf16 pairs
            uint32_t wpk[4][2];
#pragma unroll
            for (int ks = 0; ks < 4; ++ks) {
                float w4[4];
#pragma unroll
                for (int r = 0; r < 4; ++r) {
                    const float x = st[ks][r] * 0.125f;
                    float e = fmaxf(x, 0.f) + __expf(fminf(x, 0.f));
                    e = e * e;
                    w4[r] = e;
                    dpart[qs] += e;
                }
                wpk[ks][0] = (uint32_t)f2bf(w4[0]) | ((uint32_t)f2bf(w4[1]) << 16);
                wpk[ks][1] = (uint32_t)f2bf(w4[2]) | ((uint32_t)f2bf(w4[3]) << 16);
            }
            // repack W^T C-frags -> PV B-operand (16 shfls)
#pragma unroll
            for (int kh = 0; kh < 2; ++kh) {
                const uint32_t a0 = (uint32_t)__shfl((int)wpk[2 * kh][0], sA, 64);
                const uint32_t a1 = (uint32_t)__shfl((int)wpk[2 * kh][1], sA, 64);
                const uint32_t a2 = (uint32_t)__shfl((int)wpk[2 * kh][0], sB, 64);
                const uint32_t a3 = (uint32_t)__shfl((int)wpk[2 * kh][1], sB, 64);
                const uint32_t b0 = (uint32_t)__shfl((int)wpk[2 * kh + 1][0], sA, 64);
                const uint32_t b1 = (uint32_t)__shfl((int)wpk[2 * kh + 1][1], sA, 64);
                const uint32_t b2 = (uint32_t)__shfl((int)wpk[2 * kh + 1][0], sB, 64);
                const uint32_t b3 = (uint32_t)__shfl((int)wpk[2 * kh + 1][1], sB, 64);
                BF16x8U bb;
                bb.u[0] = hi ? b0 : a0;
                bb.u[1] = hi ? b1 : a1;
                bb.u[2] = hi ? b2 : a2;
                bb.u[3] = hi ? b3 : a3;
#pragma unroll
                for (int ds = 0; ds < 4; ++ds)
                    ct[qs][ds] = __builtin_amdgcn_mfma_f32_16x16x32_bf16(
                        vf[ds][kh], bb.v, ct[qs][ds], 0, 0, 0);
            }
        }
    }

    // ---- cross-wave reduction ----
    __shared__ float accs[4][64][72];   // 73,728 B (pad 72: 16B-aligned rows)
    __shared__ float dens[4][64];
#pragma unroll
    for (int qs = 0; qs < 4; ++qs) {
        const int q = qs * 16 + l15;
#pragma unroll
        for (int ds = 0; ds < 4; ++ds) {
            *reinterpret_cast<f32x4*>(&accs[wv][q][ds * 16 + lg * 4]) = ct[qs][ds];
        }
        float dp = dpart[qs];
        dp += __shfl_xor(dp, 16, 64);
        dp += __shfl_xor(dp, 32, 64);
        if (lg == 0) dens[wv][q] = dp;
    }
    __syncthreads();
    const int q = threadIdx.x >> 2;
    const int dbase = (threadIdx.x & 3) * 16;
    const float dn = 1.f / (dens[0][q] + dens[1][q] + dens[2][q] + dens[3][q] + 1e-6f);
    const unsigned short* Vh = Vb + ((size_t)h * N_TOK + (q0 + q)) * DH;
    unsigned short* Mrow = Mout + (size_t)(q0 + q) * D_MODEL + h * DH;
#pragma unroll
    for (int t = 0; t < 4; ++t) {
        const int d = dbase + t * 4;
        f32x4 s0 = *reinterpret_cast<const f32x4*>(&accs[0][q][d]);
        f32x4 s1 = *reinterpret_cast<const f32x4*>(&accs[1][q][d]);
        f32x4 s2 = *reinterpret_cast<const f32x4*>(&accs[2][q][d]);
        f32x4 s3 = *reinterpret_cast<const f32x4*>(&accs[3][q][d]);
        const us4v vv = *reinterpret_cast<const us4v*>(&Vh[d]);
        us4v o;
#pragma unroll
        for (int r = 0; r < 4; ++r) {
            const float a = s0[r] + s1[r] + s2[r] + s3[r];
            o[r] = f2bf(a * dn - bf2f(vv[r]));
        }
        *reinterpret_cast<us4v*>(&Mrow[d]) = o;
    }
}

// ---------------------------------------------------------------------------
// O = rmsnorm(X + R); fp32 out always, bf16 out if WB.
// ---------------------------------------------------------------------------
template<int WB>
__global__ __launch_bounds__(256) void rms_resid2(
    const float* __restrict__ X, const float* __restrict__ R,
    float* __restrict__ O32, unsigned short* __restrict__ Obf) {
    const int row = blockIdx.x;
    const int tid = threadIdx.x;
    const float4 xv = reinterpret_cast<const float4*>(X + (size_t)row * D_MODEL)[tid];
    const float4 rv = reinterpret_cast<const float4*>(R + (size_t)row * D_MODEL)[tid];
    const float t0 = xv.x + rv.x, t1 = xv.y + rv.y, t2 = xv.z + rv.z, t3 = xv.w + rv.w;
    float ss = t0 * t0 + t1 * t1 + t2 * t2 + t3 * t3;
#pragma unroll
    for (int off = 32; off > 0; off >>= 1) ss += __shfl_xor(ss, off, 64);
    __shared__ float red[4];
    if ((tid & 63) == 0) red[tid >> 6] = ss;
    __syncthreads();
    const float tot = red[0] + red[1] + red[2] + red[3];
    const float rs = rsqrtf(tot * (1.f / D_MODEL) + 1e-5f);
    float4 o;
    o.x = t0 * rs; o.y = t1 * rs; o.z = t2 * rs; o.w = t3 * rs;
    reinterpret_cast<float4*>(O32 + (size_t)row * D_MODEL)[tid] = o;
    if (WB) {
        us4v ob;
        ob[0] = f2bf(o.x); ob[1] = f2bf(o.y); ob[2] = f2bf(o.z); ob[3] = f2bf(o.w);
        *reinterpret_cast<us4v*>(&Obf[(size_t)row * D_MODEL + tid * 4]) = ob;
    }
}

// Hf = silu(G)*U from GU bf16 [4096][5632]; out bf16 [4096][2816]
__global__ __launch_bounds__(256) void silu_mul_bf(
    const unsigned short* __restrict__ GU, unsigned short* __restrict__ Hf) {
    const size_t idx = (size_t)blockIdx.x * 256 + threadIdx.x;
    const int c8 = (int)(idx % (INNER / 8)) * 8;
    const int n = (int)(idx / (INNER / 8));
    us8v g = *reinterpret_cast<const us8v*>(&GU[(size_t)n * (2 * INNER) + c8]);
    us8v u = *reinterpret_cast<const us8v*>(&GU[(size_t)n * (2 * INNER) + INNER + c8]);
    us8v o;
#pragma unroll
    for (int j = 0; j < 8; ++j) {
        const float gv = bf2f(g[j]);
        o[j] = f2bf(silu_f(gv) * bf2f(u[j]));
    }
    *reinterpret_cast<us8v*>(&Hf[(size_t)n * INNER + c8]) = o;
}

// depthwise conv k=3 pad=1 + bias + silu; bf16 in/out, fp32 math
__global__ __launch_bounds__(256) void dwconv_bf(
    const unsigned short* __restrict__ Hf, const float* __restrict__ W,
    const float* __restrict__ Bv, unsigned short* __restrict__ Hc) {
    const size_t idx = (size_t)blockIdx.x * 256 + threadIdx.x;
    const int c8 = (int)(idx % (INNER / 8)) * 8;
    const int n = (int)(idx / (INNER / 8));
    float a[8];
    {
        float4 b0 = *reinterpret_cast<const float4*>(&Bv[c8]);
        float4 b1 = *reinterpret_cast<const float4*>(&Bv[c8 + 4]);
        a[0] = b0.x; a[1] = b0.y; a[2] = b0.z; a[3] = b0.w;
        a[4] = b1.x; a[5] = b1.y; a[6] = b1.z; a[7] = b1.w;
    }
#pragma unroll
    for (int k = 0; k < 3; ++k) {
        const int nn = n + k - 1;
        if (nn >= 0 && nn < N_TOK) {
            us8v x = *reinterpret_cast<const us8v*>(&Hf[(size_t)nn * INNER + c8]);
            float4 w0 = *reinterpret_cast<const float4*>(&W[(size_t)k * INNER + c8]);
            float4 w1 = *reinterpret_cast<const float4*>(&W[(size_t)k * INNER + c8 + 4]);
            a[0] += bf2f(x[0]) * w0.x; a[1] += bf2f(x[1]) * w0.y;
            a[2] += bf2f(x[2]) * w0.z; a[3] += bf2f(x[3]) * w0.w;
            a[4] += bf2f(x[4]) * w1.x; a[5] += bf2f(x[5]) * w1.y;
            a[6] += bf2f(x[6]) * w1.z; a[7] += bf2f(x[7]) * w1.w;
        }
    }
    us8v o;
#pragma unroll
    for (int j = 0; j < 8; ++j) o[j] = f2bf(silu_f(a[j]));
    *reinterpret_cast<us8v*>(&Hc[(size_t)n * INNER + c8]) = o;
}

extern "C" void kernel_launch(void* const* d_in, const int* in_sizes, int n_in,
                              void* d_out, int out_size, void* d_ws, size_t ws_size,
                              hipStream_t stream) {
    const float* Qin   = (const float*)d_in[0];
    const float* cosb  = (const float*)d_in[1];
    const float* sinb  = (const float*)d_in[2];
    const float* Wqkv  = (const float*)d_in[3];
    const float* Wo    = (const float*)d_in[4];
    const float* Wup   = (const float*)d_in[5];
    const float* convw = (const float*)d_in[6];
    const float* convb = (const float*)d_in[7];
    const float* Wdown = (const float*)d_in[8];
    float* out = (float*)d_out;
    float* ws  = (float*)d_ws;

    // ---- workspace layout (float-unit offsets; peak 34,734,080 f = 139 MB)
    unsigned short* WqkvT  = (unsigned short*)(ws);              // [3072][1024]
    unsigned short* WoT    = (unsigned short*)(ws + 1572864);    // [1024][1024]
    unsigned short* WupT   = (unsigned short*)(ws + 2097152);    // [5632][1024]
    unsigned short* WdownT = (unsigned short*)(ws + 4980736);    // [1024][2816]
    unsigned short* Qin_bf = (unsigned short*)(ws + 6422528);    // [4096][1024]
    unsigned short* mcat   = (unsigned short*)(ws + 6422528);    // reuse (after GEMM1)
    float*          qkv32  = ws + 8519680;                       // [4096][3072]
    float*          wo32   = ws + 8519680;                       // reuse (after rope)
    unsigned short* GU     = (unsigned short*)(ws + 8519680);    // [4096][5632] (after rms)
    unsigned short* Hc     = (unsigned short*)(ws + 8519680);    // [4096][2816] (after silu+conv)
    float*          dn32   = ws + 14286848;                      // [4096][1024]
    unsigned short* Qb     = (unsigned short*)(ws + 21102592);
    unsigned short* Kb     = (unsigned short*)(ws + 23199744);
    unsigned short* Vt     = (unsigned short*)(ws + 25296896);
    unsigned short* Vb     = (unsigned short*)(ws + 27394048);
    unsigned short* Hf     = (unsigned short*)(ws + 21102592);   // reuse (after attn)
    float*          Qi32   = ws + 29491200;                      // [4096][1024]
    unsigned short* Qi_bf  = (unsigned short*)(ws + 33685504);   // [4096][1024]

    const dim3 blk(256);
    // 0. weight / input prep
    cvt_bf16<<<2048, blk, 0, stream>>>(Qin, Qin_bf);
    transpose_bf16<<<dim3(48, 16), blk, 0, stream>>>(Wqkv, WqkvT, 1024, 3072);
    transpose_bf16<<<dim3(16, 16), blk, 0, stream>>>(Wo, WoT, 1024, 1024);
    transpose_bf16<<<dim3(88, 16), blk, 0, stream>>>(Wup, WupT, 1024, 5632);
    transpose_bf16<<<dim3(16, 44), blk, 0, stream>>>(Wdown, WdownT, 2816, 1024);
    // 1. QKV projection (fp32 out for RoPE/RMS precision)
    gemm_bf16<0><<<dim3(24, 32), blk, 0, stream>>>(
        Qin_bf, WqkvT, qkv32, 4096, 3072, 1024);
    // 2. RoPE + RMS + transposes
    rope_norm2<<<dim3(64, 16), blk, 0, stream>>>(qkv32, cosb, sinb, Qb, Kb, Vt, Vb);
    // 3. attention -> m_concat (bf16); flat grid with XCD-clustered decode
    attn_mfma2<<<1024, blk, 0, stream>>>(Qb, Kb, Vt, Vb, mcat);
    // 4. W_o projection (fp32 out)
    gemm_bf16<0><<<dim3(8, 32), blk, 0, stream>>>(
        mcat, WoT, wo32, 4096, 1024, 1024);
    // 5. Q_interact = rmsnorm(Q_in + wo_out) -> fp32 + bf16
    rms_resid2<1><<<4096, blk, 0, stream>>>(wo32, Qin, Qi32, Qi_bf);
    // 6. GU = Qi @ Wup (bf16 out)
    gemm_bf16<1><<<dim3(44, 32), blk, 0, stream>>>(
        Qi_bf, WupT, GU, 4096, 5632, 1024);
    // 7. Hf = silu(G)*U
    silu_mul_bf<<<5632, blk, 0, stream>>>(GU, Hf);
    // 8. depthwise conv + bias + silu
    dwconv_bf<<<5632, blk, 0, stream>>>(Hf, convw, convb, Hc);
    // 9. W_down projection (fp32 out)
    gemm_bf16<0><<<dim3(8, 32), blk, 0, stream>>>(
        Hc, WdownT, dn32, 4096, 1024, 2816);
    // 10. out = rmsnorm(Qi + dn)
    rms_resid2<0><<<4096, blk, 0, stream>>>(dn32, Qi32, out, nullptr);
}